// Round 4
// baseline (47.099 us; speedup 1.0000x reference)
//
#include <hip/hip_runtime.h>

typedef float f32x4 __attribute__((ext_vector_type(4)));

#define BB 16384
#define DD 1024
#define NBLK 1024
#define NWAVES (NBLK * 4)            // 4096 waves
// each wave handles BB/NWAVES = 4 rows, grid-stride

__global__ __launch_bounds__(256) void cross_compress_kernel(
    const float* __restrict__ enc_user,
    const float* __restrict__ enc_item,
    const float* __restrict__ t_vv,
    const float* __restrict__ t_ev,
    const float* __restrict__ t_ve,
    const float* __restrict__ t_ee,
    const float* __restrict__ b_v,
    const float* __restrict__ b_e,
    float* __restrict__ out)   // [0:B*D) = v_out, [B*D:2*B*D) = e_out
{
    const int tid  = threadIdx.x;
    const int lane = tid & 63;
    const int gw   = blockIdx.x * 4 + (tid >> 6);   // global wave id
    const int c0   = lane << 2;                     // chunk k at c0 + 256*k

    // Hoisted theta/bias slices: loaded ONCE per wave, reused for all rows.
    f32x4 vv[4], ev[4], ve[4], ee[4], bv[4], be[4];
    #pragma unroll
    for (int k = 0; k < 4; ++k) {
        const int c = c0 + 256 * k;
        vv[k] = *reinterpret_cast<const f32x4*>(t_vv + c);
        ev[k] = *reinterpret_cast<const f32x4*>(t_ev + c);
        ve[k] = *reinterpret_cast<const f32x4*>(t_ve + c);
        ee[k] = *reinterpret_cast<const f32x4*>(t_ee + c);
        bv[k] = *reinterpret_cast<const f32x4*>(b_v + c);
        be[k] = *reinterpret_cast<const f32x4*>(b_e + c);
    }

    for (int r = gw; r < BB; r += NWAVES) {
        const long base = (long)r * DD;

        // 8 outstanding dwordx4 loads per row (4 contiguous-1KB chunks x 2 inputs)
        f32x4 u[4], it[4];
        #pragma unroll
        for (int k = 0; k < 4; ++k) {
            u[k]  = *reinterpret_cast<const f32x4*>(enc_user + base + c0 + 256 * k);
            it[k] = *reinterpret_cast<const f32x4*>(enc_item + base + c0 + 256 * k);
        }

        // Partial dots over this lane's 16 elements:
        //   s0=e_vv (it.t_vv)  s1=v_ev (u.t_ev)  s2=e_ve (it.t_ve)  s3=v_ee (u.t_ee)
        float s0 = 0.f, s1 = 0.f, s2 = 0.f, s3 = 0.f;
        #pragma unroll
        for (int k = 0; k < 4; ++k) {
            s0 += it[k].x*vv[k].x + it[k].y*vv[k].y + it[k].z*vv[k].z + it[k].w*vv[k].w;
            s1 +=  u[k].x*ev[k].x +  u[k].y*ev[k].y +  u[k].z*ev[k].z +  u[k].w*ev[k].w;
            s2 += it[k].x*ve[k].x + it[k].y*ve[k].y + it[k].z*ve[k].z + it[k].w*ve[k].w;
            s3 +=  u[k].x*ee[k].x +  u[k].y*ee[k].y +  u[k].z*ee[k].z +  u[k].w*ee[k].w;
        }

        // 64-lane butterfly reduce — no LDS, no __syncthreads
        #pragma unroll
        for (int off = 32; off > 0; off >>= 1) {
            s0 += __shfl_xor(s0, off);
            s1 += __shfl_xor(s1, off);
            s2 += __shfl_xor(s2, off);
            s3 += __shfl_xor(s3, off);
        }

        // Fused elementwise outputs, nontemporal streaming stores
        #pragma unroll
        for (int k = 0; k < 4; ++k) {
            f32x4 vo, eo;
            vo.x = u[k].x*s0 + it[k].x*s1 + bv[k].x;
            vo.y = u[k].y*s0 + it[k].y*s1 + bv[k].y;
            vo.z = u[k].z*s0 + it[k].z*s1 + bv[k].z;
            vo.w = u[k].w*s0 + it[k].w*s1 + bv[k].w;
            eo.x = u[k].x*s2 + it[k].x*s3 + be[k].x;
            eo.y = u[k].y*s2 + it[k].y*s3 + be[k].y;
            eo.z = u[k].z*s2 + it[k].z*s3 + be[k].z;
            eo.w = u[k].w*s2 + it[k].w*s3 + be[k].w;
            __builtin_nontemporal_store(vo,
                reinterpret_cast<f32x4*>(out + base + c0 + 256 * k));
            __builtin_nontemporal_store(eo,
                reinterpret_cast<f32x4*>(out + (long)BB * DD + base + c0 + 256 * k));
        }
    }
}

extern "C" void kernel_launch(void* const* d_in, const int* in_sizes, int n_in,
                              void* d_out, int out_size, void* d_ws, size_t ws_size,
                              hipStream_t stream) {
    const float* enc_user = (const float*)d_in[0];
    const float* enc_item = (const float*)d_in[1];
    const float* t_vv     = (const float*)d_in[2];
    const float* t_ev     = (const float*)d_in[3];
    const float* t_ve     = (const float*)d_in[4];
    const float* t_ee     = (const float*)d_in[5];
    const float* b_v      = (const float*)d_in[6];
    const float* b_e      = (const float*)d_in[7];
    float* out = (float*)d_out;

    cross_compress_kernel<<<dim3(NBLK), dim3(256), 0, stream>>>(
        enc_user, enc_item, t_vv, t_ev, t_ve, t_ee, b_v, b_e, out);
}

// Round 5
// 44.119 us; speedup vs baseline: 1.0675x; 1.0675x over previous
//
#include <hip/hip_runtime.h>

typedef float f32x4 __attribute__((ext_vector_type(4)));

#define BB 16384
#define DD 1024
#define RPB 4            // rows per 256-thread block; grid = BB/RPB = 4096

__global__ __launch_bounds__(256) void cross_compress_kernel(
    const float* __restrict__ enc_user,
    const float* __restrict__ enc_item,
    const float* __restrict__ t_vv,
    const float* __restrict__ t_ev,
    const float* __restrict__ t_ve,
    const float* __restrict__ t_ee,
    const float* __restrict__ b_v,
    const float* __restrict__ b_e,
    float* __restrict__ out)   // [0:B*D) = v_out, [B*D:2*B*D) = e_out
{
    const int tid = threadIdx.x;
    const int c   = tid << 2;                  // this thread's column (float4)
    const long r0 = (long)blockIdx.x * RPB;

    // Per-thread theta/bias slice: one f32x4 each (24 VGPRs), shared by all rows.
    const f32x4 vv = *reinterpret_cast<const f32x4*>(t_vv + c);
    const f32x4 ev = *reinterpret_cast<const f32x4*>(t_ev + c);
    const f32x4 ve = *reinterpret_cast<const f32x4*>(t_ve + c);
    const f32x4 ee = *reinterpret_cast<const f32x4*>(t_ee + c);
    const f32x4 bv = *reinterpret_cast<const f32x4*>(b_v + c);
    const f32x4 be = *reinterpret_cast<const f32x4*>(b_e + c);

    // Issue all 8 row loads up front: 128 B in flight per lane (4x R1's MLP).
    f32x4 u[RPB], it[RPB];
    #pragma unroll
    for (int r = 0; r < RPB; ++r) {
        const long base = (r0 + r) * DD;
        u[r]  = *reinterpret_cast<const f32x4*>(enc_user + base + c);
        it[r] = *reinterpret_cast<const f32x4*>(enc_item + base + c);
    }

    // Partial dots per row: s_vv=it.t_vv  s_ev=u.t_ev  s_ve=it.t_ve  s_ee=u.t_ee
    float s_vv[RPB], s_ev[RPB], s_ve[RPB], s_ee[RPB];
    #pragma unroll
    for (int r = 0; r < RPB; ++r) {
        s_vv[r] = it[r].x*vv.x + it[r].y*vv.y + it[r].z*vv.z + it[r].w*vv.w;
        s_ev[r] =  u[r].x*ev.x +  u[r].y*ev.y +  u[r].z*ev.z +  u[r].w*ev.w;
        s_ve[r] = it[r].x*ve.x + it[r].y*ve.y + it[r].z*ve.z + it[r].w*ve.w;
        s_ee[r] =  u[r].x*ee.x +  u[r].y*ee.y +  u[r].z*ee.z +  u[r].w*ee.w;
    }

    // 64-lane butterfly reduce for all 16 partials.
    #pragma unroll
    for (int off = 32; off > 0; off >>= 1) {
        #pragma unroll
        for (int r = 0; r < RPB; ++r) {
            s_vv[r] += __shfl_xor(s_vv[r], off);
            s_ev[r] += __shfl_xor(s_ev[r], off);
            s_ve[r] += __shfl_xor(s_ve[r], off);
            s_ee[r] += __shfl_xor(s_ee[r], off);
        }
    }

    // Single cross-wave combine for all 4 rows (one barrier per 4 rows).
    __shared__ float red[RPB][4][4];
    const int wave = tid >> 6;
    if ((tid & 63) == 0) {
        #pragma unroll
        for (int r = 0; r < RPB; ++r) {
            red[r][wave][0] = s_vv[r];
            red[r][wave][1] = s_ev[r];
            red[r][wave][2] = s_ve[r];
            red[r][wave][3] = s_ee[r];
        }
    }
    __syncthreads();

    #pragma unroll
    for (int r = 0; r < RPB; ++r) {
        const float e_vv = red[r][0][0] + red[r][1][0] + red[r][2][0] + red[r][3][0];
        const float v_ev = red[r][0][1] + red[r][1][1] + red[r][2][1] + red[r][3][1];
        const float e_ve = red[r][0][2] + red[r][1][2] + red[r][2][2] + red[r][3][2];
        const float v_ee = red[r][0][3] + red[r][1][3] + red[r][2][3] + red[r][3][3];

        const long base = (r0 + r) * DD;
        f32x4 vo, eo;
        vo.x = u[r].x*e_vv + it[r].x*v_ev + bv.x;
        vo.y = u[r].y*e_vv + it[r].y*v_ev + bv.y;
        vo.z = u[r].z*e_vv + it[r].z*v_ev + bv.z;
        vo.w = u[r].w*e_vv + it[r].w*v_ev + bv.w;
        eo.x = u[r].x*e_ve + it[r].x*v_ee + be.x;
        eo.y = u[r].y*e_ve + it[r].y*v_ee + be.y;
        eo.z = u[r].z*e_ve + it[r].z*v_ee + be.z;
        eo.w = u[r].w*e_ve + it[r].w*v_ee + be.w;

        __builtin_nontemporal_store(vo, reinterpret_cast<f32x4*>(out + base + c));
        __builtin_nontemporal_store(eo, reinterpret_cast<f32x4*>(out + (long)BB*DD + base + c));
    }
}

extern "C" void kernel_launch(void* const* d_in, const int* in_sizes, int n_in,
                              void* d_out, int out_size, void* d_ws, size_t ws_size,
                              hipStream_t stream) {
    const float* enc_user = (const float*)d_in[0];
    const float* enc_item = (const float*)d_in[1];
    const float* t_vv     = (const float*)d_in[2];
    const float* t_ev     = (const float*)d_in[3];
    const float* t_ve     = (const float*)d_in[4];
    const float* t_ee     = (const float*)d_in[5];
    const float* b_v      = (const float*)d_in[6];
    const float* b_e      = (const float*)d_in[7];
    float* out = (float*)d_out;

    cross_compress_kernel<<<dim3(BB / RPB), dim3(256), 0, stream>>>(
        enc_user, enc_item, t_vv, t_ev, t_ve, t_ee, b_v, b_e, out);
}

// Round 6
// 42.803 us; speedup vs baseline: 1.1003x; 1.0307x over previous
//
#include <hip/hip_runtime.h>

#define BB 16384
#define DD 1024
// Block-per-row, 256 threads (4 waves), one f32x4 per thread covers D=1024.
// ROOFLINE NOTE: per invocation this kernel moves the mandatory minimum
// 268.4 MB (134 read + 134 write, each byte once, fully coalesced dwordx4).
// Measured 43.42 us = 6.18 TB/s demand-side = 98.3% of the 6.29 TB/s
// float4-copy ceiling (m13). R4 (wave-per-row) and R5 (4 rows/block, 4x MLP,
// 2x occupancy) both landed within noise/worse -> bandwidth-bound, not
// latency-bound. nt stores: neutral (memory-side L3 ignores the hint) but
// kept from the best-measured build.

typedef float f32x4 __attribute__((ext_vector_type(4)));

__global__ __launch_bounds__(256) void cross_compress_kernel(
    const float* __restrict__ enc_user,
    const float* __restrict__ enc_item,
    const float* __restrict__ t_vv,
    const float* __restrict__ t_ev,
    const float* __restrict__ t_ve,
    const float* __restrict__ t_ee,
    const float* __restrict__ b_v,
    const float* __restrict__ b_e,
    float* __restrict__ out)   // [0:B*D) = v_out, [B*D:2*B*D) = e_out
{
    const int row  = blockIdx.x;
    const int tid  = threadIdx.x;
    const int c    = tid << 2;                 // column of this thread's float4
    const long base = (long)row * DD;

    const f32x4 u  = *reinterpret_cast<const f32x4*>(enc_user + base + c);
    const f32x4 it = *reinterpret_cast<const f32x4*>(enc_item + base + c);
    const f32x4 vv = *reinterpret_cast<const f32x4*>(t_vv + c);
    const f32x4 ev = *reinterpret_cast<const f32x4*>(t_ev + c);
    const f32x4 ve = *reinterpret_cast<const f32x4*>(t_ve + c);
    const f32x4 ee = *reinterpret_cast<const f32x4*>(t_ee + c);

    // Partial dot products (per reference):
    //   e_vv = enc_item . t_vv ; v_ev = enc_user . t_ev
    //   e_ve = enc_item . t_ve ; v_ee = enc_user . t_ee
    float s0 = it.x*vv.x + it.y*vv.y + it.z*vv.z + it.w*vv.w;  // e_vv
    float s1 =  u.x*ev.x +  u.y*ev.y +  u.z*ev.z +  u.w*ev.w;  // v_ev
    float s2 = it.x*ve.x + it.y*ve.y + it.z*ve.z + it.w*ve.w;  // e_ve
    float s3 =  u.x*ee.x +  u.y*ee.y +  u.z*ee.z +  u.w*ee.w;  // v_ee

    // 64-lane butterfly reduce within each wave
    #pragma unroll
    for (int off = 32; off > 0; off >>= 1) {
        s0 += __shfl_xor(s0, off);
        s1 += __shfl_xor(s1, off);
        s2 += __shfl_xor(s2, off);
        s3 += __shfl_xor(s3, off);
    }

    // Cross-wave combine: 4 waves x 4 sums in LDS, broadcast read back.
    __shared__ float red[4][4];
    const int wave = tid >> 6;
    if ((tid & 63) == 0) {
        red[wave][0] = s0; red[wave][1] = s1;
        red[wave][2] = s2; red[wave][3] = s3;
    }
    __syncthreads();

    const float e_vv = red[0][0] + red[1][0] + red[2][0] + red[3][0];
    const float v_ev = red[0][1] + red[1][1] + red[2][1] + red[3][1];
    const float e_ve = red[0][2] + red[1][2] + red[2][2] + red[3][2];
    const float v_ee = red[0][3] + red[1][3] + red[2][3] + red[3][3];

    const f32x4 bv = *reinterpret_cast<const f32x4*>(b_v + c);
    const f32x4 be = *reinterpret_cast<const f32x4*>(b_e + c);

    f32x4 vo, eo;
    vo.x = u.x*e_vv + it.x*v_ev + bv.x;
    vo.y = u.y*e_vv + it.y*v_ev + bv.y;
    vo.z = u.z*e_vv + it.z*v_ev + bv.z;
    vo.w = u.w*e_vv + it.w*v_ev + bv.w;

    eo.x = u.x*e_ve + it.x*v_ee + be.x;
    eo.y = u.y*e_ve + it.y*v_ee + be.y;
    eo.z = u.z*e_ve + it.z*v_ee + be.z;
    eo.w = u.w*e_ve + it.w*v_ee + be.w;

    __builtin_nontemporal_store(vo, reinterpret_cast<f32x4*>(out + base + c));
    __builtin_nontemporal_store(eo, reinterpret_cast<f32x4*>(out + (long)BB * DD + base + c));
}

extern "C" void kernel_launch(void* const* d_in, const int* in_sizes, int n_in,
                              void* d_out, int out_size, void* d_ws, size_t ws_size,
                              hipStream_t stream) {
    const float* enc_user = (const float*)d_in[0];
    const float* enc_item = (const float*)d_in[1];
    const float* t_vv     = (const float*)d_in[2];
    const float* t_ev     = (const float*)d_in[3];
    const float* t_ve     = (const float*)d_in[4];
    const float* t_ee     = (const float*)d_in[5];
    const float* b_v      = (const float*)d_in[6];
    const float* b_e      = (const float*)d_in[7];
    float* out = (float*)d_out;

    cross_compress_kernel<<<dim3(BB), dim3(256), 0, stream>>>(
        enc_user, enc_item, t_vv, t_ev, t_ve, t_ee, b_v, b_e, out);
}